// Round 1
// 552.153 us; speedup vs baseline: 1.0399x; 1.0399x over previous
//
#include <hip/hip_runtime.h>
#include <hip/hip_bf16.h>
#include <stdint.h>

typedef __bf16 bf16x8 __attribute__((ext_vector_type(8)));
typedef float  f32x4  __attribute__((ext_vector_type(4)));
typedef unsigned short u16x8 __attribute__((ext_vector_type(8)));

// ---- helpers ---------------------------------------------------------------

__device__ __forceinline__ unsigned short f32_to_bf16_rne(float f) {
  union { float f; unsigned int u; } v; v.f = f;
  unsigned int u = v.u;
  unsigned int r = u + 0x7fffu + ((u >> 16) & 1u);  // round-to-nearest-even
  return (unsigned short)(r >> 16);
}

// async global->LDS, 16B per lane. LDS dest is wave-uniform base; HW scatters
// lane i at base + i*16 (guide §5 caveat, m104/m108).
__device__ __forceinline__ void async16(const unsigned short* g, unsigned short* l) {
  __builtin_amdgcn_global_load_lds(
      (const __attribute__((address_space(1))) unsigned int*)g,
      (__attribute__((address_space(3))) unsigned int*)l,
      16, 0, 0);
}

// ---- kernel 1 (fused): W' = W + 2*(lora_B@lora_A) -> bf16 ; x -> bf16 ------
// unchanged from 574us version (pure streaming, ~290MB moved).
__global__ __launch_bounds__(256) void prep_fused(const float* __restrict__ W,
                                                  const float* __restrict__ lA,
                                                  const float* __restrict__ lB,
                                                  const float* __restrict__ x,
                                                  unsigned short* __restrict__ Wp,
                                                  unsigned short* __restrict__ xb) {
  const int b   = blockIdx.x;
  const int tid = threadIdx.x;
  if (b < 2048) {
    const int ro = (b & 511) * 8;                    // row group: 8 rows
    const int k  = (b >> 9) * 1024 + tid * 4;        // k strip
    float4 a[16];
    #pragma unroll
    for (int r = 0; r < 16; ++r)
      a[r] = *(const float4*)(lA + (size_t)r * 4096 + k);
    #pragma unroll
    for (int i = 0; i < 8; ++i) {
      const int o = ro + i;
      float4 acc = *(const float4*)(W + (size_t)o * 4096 + k);
      #pragma unroll
      for (int r = 0; r < 16; ++r) {
        const float s = lB[o * 16 + r] * 2.0f;       // wave-uniform -> s_load
        acc.x += s * a[r].x; acc.y += s * a[r].y;
        acc.z += s * a[r].z; acc.w += s * a[r].w;
      }
      ushort4 ov;
      ov.x = f32_to_bf16_rne(acc.x);
      ov.y = f32_to_bf16_rne(acc.y);
      ov.z = f32_to_bf16_rne(acc.z);
      ov.w = f32_to_bf16_rne(acc.w);
      *(ushort4*)(Wp + (size_t)o * 4096 + k) = ov;
    }
  } else {
    const int cb = b - 2048;
    #pragma unroll
    for (int it = 0; it < 4; ++it) {
      const size_t g8 = (size_t)cb * 1024 + it * 256 + tid;  // group-of-8 idx
      const float4* p = (const float4*)x + g8 * 2;
      const float4 f0 = p[0], f1 = p[1];
      u16x8 o;
      o[0] = f32_to_bf16_rne(f0.x); o[1] = f32_to_bf16_rne(f0.y);
      o[2] = f32_to_bf16_rne(f0.z); o[3] = f32_to_bf16_rne(f0.w);
      o[4] = f32_to_bf16_rne(f1.x); o[5] = f32_to_bf16_rne(f1.y);
      o[6] = f32_to_bf16_rne(f1.z); o[7] = f32_to_bf16_rne(f1.w);
      *((u16x8*)xb + g8) = o;
    }
  }
}

// ---- fallback GEMM (old m97-structure 128x128, f32-A path) -----------------
#define BM 128
#define BN 128
#define BK 32
#define GEMM_M 8192
#define GEMM_N 4096
#define GEMM_K 4096

template <bool A_F32>
__global__ __launch_bounds__(256) void gemm_bias(
    const void* __restrict__ Aptr,
    const unsigned short* __restrict__ B,
    const float* __restrict__ bias,
    float* __restrict__ C) {
  __shared__ __align__(16) unsigned short sA[BM * BK];
  __shared__ __align__(16) unsigned short sB[BM * BK];

  const int tid  = threadIdx.x;
  const int wave = tid >> 6;
  const int lane = tid & 63;

  const int srow = tid >> 2;
  const int scol = (tid & 3) << 3;

  const size_t a_row0 = (size_t)blockIdx.y * BM;
  const size_t b_row0 = (size_t)blockIdx.x * BN;

  const unsigned short* bg0 = B + (b_row0 +      srow) * GEMM_K + scol;
  const unsigned short* bg1 = B + (b_row0 + 64 + srow) * GEMM_K + scol;

  unsigned short* sA0 = sA +        wave * 512;
  unsigned short* sA1 = sA + 2048 + wave * 512;
  unsigned short* sB0 = sB +        wave * 512;
  unsigned short* sB1 = sB + 2048 + wave * 512;

  const unsigned short* ag0 = nullptr; const unsigned short* ag1 = nullptr;
  const float* af0 = nullptr; const float* af1 = nullptr;
  if constexpr (A_F32) {
    af0 = (const float*)Aptr + (a_row0 +      srow) * GEMM_K + scol;
    af1 = (const float*)Aptr + (a_row0 + 64 + srow) * GEMM_K + scol;
  } else {
    ag0 = (const unsigned short*)Aptr + (a_row0 +      srow) * GEMM_K + scol;
    ag1 = (const unsigned short*)Aptr + (a_row0 + 64 + srow) * GEMM_K + scol;
  }
  unsigned short* sAw0 = sA +        tid * 8;
  unsigned short* sAw1 = sA + 2048 + tid * 8;

  const int wm   = (wave >> 1) * 64;
  const int wn   = (wave & 1) * 64;
  const int lrow = lane & 15;
  const int lk   = (lane >> 4) * 8;

  const unsigned short* sa_rd = sA + (wm + lrow) * BK + lk;
  const unsigned short* sb_rd = sB + (wn + lrow) * BK + lk;

  f32x4 acc[4][4];
  #pragma unroll
  for (int i = 0; i < 4; ++i)
    #pragma unroll
    for (int j = 0; j < 4; ++j)
      acc[i][j] = (f32x4){0.f, 0.f, 0.f, 0.f};

  for (int k0 = 0; k0 < GEMM_K; k0 += BK) {
    __syncthreads();
    async16(bg0 + k0, sB0);
    async16(bg1 + k0, sB1);
    if constexpr (A_F32) {
      const float* p0 = af0 + k0;
      const float* p1 = af1 + k0;
      const float4 x0 = *(const float4*)(p0);
      const float4 x1 = *(const float4*)(p0 + 4);
      const float4 y0 = *(const float4*)(p1);
      const float4 y1 = *(const float4*)(p1 + 4);
      u16x8 w0, w1;
      w0[0] = f32_to_bf16_rne(x0.x); w0[1] = f32_to_bf16_rne(x0.y);
      w0[2] = f32_to_bf16_rne(x0.z); w0[3] = f32_to_bf16_rne(x0.w);
      w0[4] = f32_to_bf16_rne(x1.x); w0[5] = f32_to_bf16_rne(x1.y);
      w0[6] = f32_to_bf16_rne(x1.z); w0[7] = f32_to_bf16_rne(x1.w);
      w1[0] = f32_to_bf16_rne(y0.x); w1[1] = f32_to_bf16_rne(y0.y);
      w1[2] = f32_to_bf16_rne(y0.z); w1[3] = f32_to_bf16_rne(y0.w);
      w1[4] = f32_to_bf16_rne(y1.x); w1[5] = f32_to_bf16_rne(y1.y);
      w1[6] = f32_to_bf16_rne(y1.z); w1[7] = f32_to_bf16_rne(y1.w);
      *(u16x8*)sAw0 = w0;
      *(u16x8*)sAw1 = w1;
    } else {
      async16(ag0 + k0, sA0);
      async16(ag1 + k0, sA1);
    }
    __syncthreads();

    bf16x8 af[4], bf[4];
    #pragma unroll
    for (int i = 0; i < 4; ++i) {
      af[i] = *(const bf16x8*)(sa_rd + i * 16 * BK);
      bf[i] = *(const bf16x8*)(sb_rd + i * 16 * BK);
    }
    #pragma unroll
    for (int i = 0; i < 4; ++i)
      #pragma unroll
      for (int j = 0; j < 4; ++j)
        acc[i][j] = __builtin_amdgcn_mfma_f32_16x16x32_bf16(af[i], bf[j], acc[i][j], 0, 0, 0);
  }

  const int row0 = (int)a_row0 + wm + (lane >> 4) * 4;
  const int col0 = (int)b_row0 + wn + lrow;
  float bv[4];
  #pragma unroll
  for (int j = 0; j < 4; ++j) bv[j] = bias[col0 + j * 16];
  #pragma unroll
  for (int i = 0; i < 4; ++i)
    #pragma unroll
    for (int j = 0; j < 4; ++j) {
      const int col = col0 + j * 16;
      #pragma unroll
      for (int r = 0; r < 4; ++r) {
        const int row = row0 + i * 16 + r;
        C[(size_t)row * GEMM_N + col] = acc[i][j][r] + bv[j];
      }
    }
}

// ---- kernel 2 (new): 256x256 8-phase GEMM (m201 template port) -------------
// T2 (XOR swizzle via pre-swizzled src + swizzled ds_read) + T3/T4 (8-phase,
// counted vmcnt(6), never 0 in main loop) + T5 (setprio around MFMA).
// 8 waves 2Mx4N, BK=64, 128 KiB LDS double-buffer, per-wave 128x64 output.
// Staging schedule (per group G_T = 4 phases computing K-tile T from buf[T&1]):
//   ph0: stage A rows 64-127,192-255 of tile T+1 -> buf[T+1&1] (not being read)
//   ph1: stage B rows   0-127 of tile T+2 -> buf[T&1]  (B consumed at ph0)
//   ph2: stage B rows 128-255 of tile T+2
//   ph3: stage A rows 0-63,128-191 of tile T+2 (those rows consumed by ph1)
//   group-end: vmcnt(6) retires exactly tile T+1's 8 loads; 6 stay in flight.
// Swizzle: 16B-col c stored at c^(row&7); chunk rows = w*8+(lane>>3) so the
// write-side permutation is the lane-constant (lane&7)^(lane>>3).

__device__ __forceinline__ bf16x8 lds_ld(const unsigned short* p) {
  return *(const bf16x8*)p;
}

template <int MLO>
__device__ __forceinline__ void mfma16(f32x4 acc[8][4],
                                       bf16x8 a0, bf16x8 a1, bf16x8 a2, bf16x8 a3,
                                       const bf16x8 (&bf)[4][2]) {
#pragma unroll
  for (int n = 0; n < 4; ++n) {
    acc[MLO][n]     = __builtin_amdgcn_mfma_f32_16x16x32_bf16(a0, bf[n][0], acc[MLO][n], 0, 0, 0);
    acc[MLO][n]     = __builtin_amdgcn_mfma_f32_16x16x32_bf16(a1, bf[n][1], acc[MLO][n], 0, 0, 0);
    acc[MLO + 1][n] = __builtin_amdgcn_mfma_f32_16x16x32_bf16(a2, bf[n][0], acc[MLO + 1][n], 0, 0, 0);
    acc[MLO + 1][n] = __builtin_amdgcn_mfma_f32_16x16x32_bf16(a3, bf[n][1], acc[MLO + 1][n], 0, 0, 0);
  }
}

#define BARRIER() asm volatile("s_barrier" ::: "memory")
#define LGKM0()   asm volatile("s_waitcnt lgkmcnt(0)" ::: "memory")
#define VM6()     asm volatile("s_waitcnt vmcnt(6)" ::: "memory")
#define VM0()     asm volatile("s_waitcnt vmcnt(0)" ::: "memory")

__global__ __launch_bounds__(512, 2) void gemm8p(
    const unsigned short* __restrict__ A,   // [8192,4096] bf16 bits (xb)
    const unsigned short* __restrict__ B,   // [4096,4096] bf16 bits (Wp)
    const float* __restrict__ bias,         // [4096]
    float* __restrict__ C) {                // [8192,4096] fp32
  __shared__ __align__(16) unsigned short sA[2 * 256 * 64];   // 64 KiB
  __shared__ __align__(16) unsigned short sB[2 * 256 * 64];   // 64 KiB

  const int tid  = threadIdx.x;
  const int w    = tid >> 6;       // 0..7
  const int lane = tid & 63;
  const int wm2  = w >> 2;         // 0..1  M half
  const int wn4  = w & 3;          // 0..3  N quarter
  const int l15  = lane & 15;
  const int l16  = lane >> 4;      // 0..3
  const int l7   = lane & 7;

  // XCD-aware bijective swizzle (512 wgs % 8 == 0)
  const int id  = (int)blockIdx.x;
  const int swz = (id & 7) * 64 + (id >> 3);
  const int by  = swz >> 4;        // 0..31 M tile
  const int bx  = swz & 15;        // 0..15 N tile

  const size_t a_row0 = (size_t)by * 256;
  const size_t b_row0 = (size_t)bx * 256;

  // staging: per-lane global src with pre-swizzled 16B column
  const int srow = w * 8 + (lane >> 3);            // row within 64-row chunk
  const int scol = (l7 ^ (lane >> 3)) * 8;         // elements
  const unsigned short* Ag = A + (a_row0 + srow) * (size_t)4096 + scol;
  const unsigned short* Bg = B + (b_row0 + srow) * (size_t)4096 + scol;
  unsigned short* sAw = sA + w * 512;              // + buf*16384 + cr*64
  unsigned short* sBw = sB + w * 512;

  // swizzled LDS read offsets (shorts); row&7 == lane&7 for all fragments
  const int offk0 = l15 * 64 + ((l16    ) ^ l7) * 8;
  const int offk1 = l15 * 64 + ((4 + l16) ^ l7) * 8;

  f32x4 acc[8][4];
  #pragma unroll
  for (int i = 0; i < 8; ++i)
    #pragma unroll
    for (int j = 0; j < 4; ++j) acc[i][j] = (f32x4){0.f, 0.f, 0.f, 0.f};

#define STAGE_A(t, cr, buf) async16(Ag + (size_t)(cr) * 4096 + (t) * 64, sAw + (buf) * 16384 + (cr) * 64)
#define STAGE_B(t, cr, buf) async16(Bg + (size_t)(cr) * 4096 + (t) * 64, sBw + (buf) * 16384 + (cr) * 64)

  // prologue: tile0 full -> buf0; tile1 B all + A rows 0-63,128-191 -> buf1
  STAGE_B(0, 0, 0); STAGE_B(0, 64, 0); STAGE_B(0, 128, 0); STAGE_B(0, 192, 0);
  STAGE_A(0, 0, 0); STAGE_A(0, 64, 0); STAGE_A(0, 128, 0); STAGE_A(0, 192, 0);
  STAGE_B(1, 0, 1); STAGE_B(1, 64, 1); STAGE_B(1, 128, 1); STAGE_B(1, 192, 1);
  STAGE_A(1, 0, 1); STAGE_A(1, 128, 1);
  VM6();            // tile0's 8 loads retired; tile1's 6 in flight
  BARRIER();

  for (int T = 0; T < 64; ++T) {
    const int cb = T & 1, nb = cb ^ 1;
    const unsigned short* sAh = sA + cb * 16384 + wm2 * 8192;
    const unsigned short* sBh = sB + cb * 16384 + wn4 * 4096;
    const bool pre1 = (T + 1 < 64);
    const bool pre2 = (T + 2 < 64);
    bf16x8 bf[4][2];
    bf16x8 a0, a1, a2, a3;

    // -------- phase 0: B frags (all) + A m0,m1 --------
    a0 = lds_ld(sAh + 0 * 1024 + offk0);
    a1 = lds_ld(sAh + 0 * 1024 + offk1);
    a2 = lds_ld(sAh + 1 * 1024 + offk0);
    a3 = lds_ld(sAh + 1 * 1024 + offk1);
    #pragma unroll
    for (int n = 0; n < 4; ++n) {
      bf[n][0] = lds_ld(sBh + n * 1024 + offk0);
      bf[n][1] = lds_ld(sBh + n * 1024 + offk1);
    }
    if (pre1) { STAGE_A(T + 1, 64, nb); STAGE_A(T + 1, 192, nb); }
    BARRIER();
    LGKM0();
    __builtin_amdgcn_s_setprio(1);
    mfma16<0>(acc, a0, a1, a2, a3, bf);
    __builtin_amdgcn_s_setprio(0);
    BARRIER();

    // -------- phase 1: A m2,m3 --------
    a0 = lds_ld(sAh + 2 * 1024 + offk0);
    a1 = lds_ld(sAh + 2 * 1024 + offk1);
    a2 = lds_ld(sAh + 3 * 1024 + offk0);
    a3 = lds_ld(sAh + 3 * 1024 + offk1);
    if (pre2) { STAGE_B(T + 2, 0, cb); STAGE_B(T + 2, 64, cb); }
    BARRIER();
    LGKM0();
    __builtin_amdgcn_s_setprio(1);
    mfma16<2>(acc, a0, a1, a2, a3, bf);
    __builtin_amdgcn_s_setprio(0);
    BARRIER();

    // -------- phase 2: A m4,m5 --------
    a0 = lds_ld(sAh + 4 * 1024 + offk0);
    a1 = lds_ld(sAh + 4 * 1024 + offk1);
    a2 = lds_ld(sAh + 5 * 1024 + offk0);
    a3 = lds_ld(sAh + 5 * 1024 + offk1);
    if (pre2) { STAGE_B(T + 2, 128, cb); STAGE_B(T + 2, 192, cb); }
    BARRIER();
    LGKM0();
    __builtin_amdgcn_s_setprio(1);
    mfma16<4>(acc, a0, a1, a2, a3, bf);
    __builtin_amdgcn_s_setprio(0);
    BARRIER();

    // -------- phase 3: A m6,m7 + group checkpoint --------
    a0 = lds_ld(sAh + 6 * 1024 + offk0);
    a1 = lds_ld(sAh + 6 * 1024 + offk1);
    a2 = lds_ld(sAh + 7 * 1024 + offk0);
    a3 = lds_ld(sAh + 7 * 1024 + offk1);
    if (pre2) { STAGE_A(T + 2, 0, cb); STAGE_A(T + 2, 128, cb); }
    BARRIER();
    LGKM0();
    __builtin_amdgcn_s_setprio(1);
    mfma16<6>(acc, a0, a1, a2, a3, bf);
    __builtin_amdgcn_s_setprio(0);
    if (T < 62) { VM6(); } else { VM0(); }   // tile T+1 fully landed
    BARRIER();
  }

  // epilogue: C/D layout col=lane&15, row=(lane>>4)*4+reg (m89-verified)
  const int erow = (int)a_row0 + wm2 * 128 + l16 * 4;
  const int ecol = (int)b_row0 + wn4 * 64 + l15;
  float bv[4];
  #pragma unroll
  for (int n = 0; n < 4; ++n) bv[n] = bias[ecol + n * 16];
  #pragma unroll
  for (int m = 0; m < 8; ++m)
    #pragma unroll
    for (int n = 0; n < 4; ++n) {
      const int col = ecol + n * 16;
      #pragma unroll
      for (int r = 0; r < 4; ++r)
        C[(size_t)(erow + m * 16 + r) * 4096 + col] = acc[m][n][r] + bv[n];
    }
}

#undef STAGE_A
#undef STAGE_B

// ---- launch ----------------------------------------------------------------

extern "C" void kernel_launch(void* const* d_in, const int* in_sizes, int n_in,
                              void* d_out, int out_size, void* d_ws, size_t ws_size,
                              hipStream_t stream) {
  const float* x  = (const float*)d_in[0];   // [4,2048,4096]
  const float* W  = (const float*)d_in[1];   // [4096,4096]
  const float* b  = (const float*)d_in[2];   // [4096]
  const float* lA = (const float*)d_in[3];   // [16,4096]
  const float* lB = (const float*)d_in[4];   // [4096,16]
  float* out = (float*)d_out;                // [4,2048,4096] fp32
  (void)in_sizes; (void)n_in; (void)out_size;

  const size_t WP_BYTES = (size_t)4096 * 4096 * 2;
  const size_t XB_BYTES = (size_t)8192 * 4096 * 2;
  unsigned short* Wp = (unsigned short*)d_ws;

  if (ws_size >= WP_BYTES + XB_BYTES) {
    unsigned short* xb = Wp + (size_t)4096 * 4096;
    prep_fused<<<6144, 256, 0, stream>>>(W, lA, lB, x, Wp, xb);
    gemm8p<<<512, 512, 0, stream>>>(xb, Wp, b, out);
  } else {
    prep_fused<<<2048, 256, 0, stream>>>(W, lA, lB, x, Wp, (unsigned short*)nullptr);
    gemm_bias<true><<<dim3(GEMM_N / BN, GEMM_M / BM), 256, 0, stream>>>(
        (const void*)x, Wp, b, out);
  }
}

// Round 2
// 522.070 us; speedup vs baseline: 1.0998x; 1.0576x over previous
//
#include <hip/hip_runtime.h>
#include <hip/hip_bf16.h>
#include <stdint.h>

typedef __bf16 bf16x8 __attribute__((ext_vector_type(8)));
typedef float  f32x4  __attribute__((ext_vector_type(4)));
typedef unsigned short u16x8 __attribute__((ext_vector_type(8)));

// ---- helpers ---------------------------------------------------------------

__device__ __forceinline__ unsigned short f32_to_bf16_rne(float f) {
  union { float f; unsigned int u; } v; v.f = f;
  unsigned int u = v.u;
  unsigned int r = u + 0x7fffu + ((u >> 16) & 1u);  // round-to-nearest-even
  return (unsigned short)(r >> 16);
}

// async global->LDS, 16B per lane. LDS dest is wave-uniform base; HW scatters
// lane i at base + i*16 (guide §5 caveat, m104/m108).
__device__ __forceinline__ void async16(const unsigned short* g, unsigned short* l) {
  __builtin_amdgcn_global_load_lds(
      (const __attribute__((address_space(1))) unsigned int*)g,
      (__attribute__((address_space(3))) unsigned int*)l,
      16, 0, 0);
}

// ---- kernel 1 (fused): W' = W + 2*(lora_B@lora_A) -> bf16 ; x -> bf16 ------
__global__ __launch_bounds__(256) void prep_fused(const float* __restrict__ W,
                                                  const float* __restrict__ lA,
                                                  const float* __restrict__ lB,
                                                  const float* __restrict__ x,
                                                  unsigned short* __restrict__ Wp,
                                                  unsigned short* __restrict__ xb) {
  const int b   = blockIdx.x;
  const int tid = threadIdx.x;
  if (b < 2048) {
    const int ro = (b & 511) * 8;                    // row group: 8 rows
    const int k  = (b >> 9) * 1024 + tid * 4;        // k strip
    float4 a[16];
    #pragma unroll
    for (int r = 0; r < 16; ++r)
      a[r] = *(const float4*)(lA + (size_t)r * 4096 + k);
    #pragma unroll
    for (int i = 0; i < 8; ++i) {
      const int o = ro + i;
      float4 acc = *(const float4*)(W + (size_t)o * 4096 + k);
      #pragma unroll
      for (int r = 0; r < 16; ++r) {
        const float s = lB[o * 16 + r] * 2.0f;       // wave-uniform -> s_load
        acc.x += s * a[r].x; acc.y += s * a[r].y;
        acc.z += s * a[r].z; acc.w += s * a[r].w;
      }
      ushort4 ov;
      ov.x = f32_to_bf16_rne(acc.x);
      ov.y = f32_to_bf16_rne(acc.y);
      ov.z = f32_to_bf16_rne(acc.z);
      ov.w = f32_to_bf16_rne(acc.w);
      *(ushort4*)(Wp + (size_t)o * 4096 + k) = ov;
    }
  } else {
    const int cb = b - 2048;
    #pragma unroll
    for (int it = 0; it < 4; ++it) {
      const size_t g8 = (size_t)cb * 1024 + it * 256 + tid;  // group-of-8 idx
      const float4* p = (const float4*)x + g8 * 2;
      const float4 f0 = p[0], f1 = p[1];
      u16x8 o;
      o[0] = f32_to_bf16_rne(f0.x); o[1] = f32_to_bf16_rne(f0.y);
      o[2] = f32_to_bf16_rne(f0.z); o[3] = f32_to_bf16_rne(f0.w);
      o[4] = f32_to_bf16_rne(f1.x); o[5] = f32_to_bf16_rne(f1.y);
      o[6] = f32_to_bf16_rne(f1.z); o[7] = f32_to_bf16_rne(f1.w);
      *((u16x8*)xb + g8) = o;
    }
  }
}

// ---- fallback GEMM (old m97-structure 128x128, f32-A path) -----------------
#define BM 128
#define BN 128
#define BK 32
#define GEMM_M 8192
#define GEMM_N 4096
#define GEMM_K 4096

template <bool A_F32>
__global__ __launch_bounds__(256) void gemm_bias(
    const void* __restrict__ Aptr,
    const unsigned short* __restrict__ B,
    const float* __restrict__ bias,
    float* __restrict__ C) {
  __shared__ __align__(16) unsigned short sA[BM * BK];
  __shared__ __align__(16) unsigned short sB[BM * BK];

  const int tid  = threadIdx.x;
  const int wave = tid >> 6;
  const int lane = tid & 63;

  const int srow = tid >> 2;
  const int scol = (tid & 3) << 3;

  const size_t a_row0 = (size_t)blockIdx.y * BM;
  const size_t b_row0 = (size_t)blockIdx.x * BN;

  const unsigned short* bg0 = B + (b_row0 +      srow) * GEMM_K + scol;
  const unsigned short* bg1 = B + (b_row0 + 64 + srow) * GEMM_K + scol;

  unsigned short* sA0 = sA +        wave * 512;
  unsigned short* sA1 = sA + 2048 + wave * 512;
  unsigned short* sB0 = sB +        wave * 512;
  unsigned short* sB1 = sB + 2048 + wave * 512;

  const unsigned short* ag0 = nullptr; const unsigned short* ag1 = nullptr;
  const float* af0 = nullptr; const float* af1 = nullptr;
  if constexpr (A_F32) {
    af0 = (const float*)Aptr + (a_row0 +      srow) * GEMM_K + scol;
    af1 = (const float*)Aptr + (a_row0 + 64 + srow) * GEMM_K + scol;
  } else {
    ag0 = (const unsigned short*)Aptr + (a_row0 +      srow) * GEMM_K + scol;
    ag1 = (const unsigned short*)Aptr + (a_row0 + 64 + srow) * GEMM_K + scol;
  }
  unsigned short* sAw0 = sA +        tid * 8;
  unsigned short* sAw1 = sA + 2048 + tid * 8;

  const int wm   = (wave >> 1) * 64;
  const int wn   = (wave & 1) * 64;
  const int lrow = lane & 15;
  const int lk   = (lane >> 4) * 8;

  const unsigned short* sa_rd = sA + (wm + lrow) * BK + lk;
  const unsigned short* sb_rd = sB + (wn + lrow) * BK + lk;

  f32x4 acc[4][4];
  #pragma unroll
  for (int i = 0; i < 4; ++i)
    #pragma unroll
    for (int j = 0; j < 4; ++j)
      acc[i][j] = (f32x4){0.f, 0.f, 0.f, 0.f};

  for (int k0 = 0; k0 < GEMM_K; k0 += BK) {
    __syncthreads();
    async16(bg0 + k0, sB0);
    async16(bg1 + k0, sB1);
    if constexpr (A_F32) {
      const float* p0 = af0 + k0;
      const float* p1 = af1 + k0;
      const float4 x0 = *(const float4*)(p0);
      const float4 x1 = *(const float4*)(p0 + 4);
      const float4 y0 = *(const float4*)(p1);
      const float4 y1 = *(const float4*)(p1 + 4);
      u16x8 w0, w1;
      w0[0] = f32_to_bf16_rne(x0.x); w0[1] = f32_to_bf16_rne(x0.y);
      w0[2] = f32_to_bf16_rne(x0.z); w0[3] = f32_to_bf16_rne(x0.w);
      w0[4] = f32_to_bf16_rne(x1.x); w0[5] = f32_to_bf16_rne(x1.y);
      w0[6] = f32_to_bf16_rne(x1.z); w0[7] = f32_to_bf16_rne(x1.w);
      w1[0] = f32_to_bf16_rne(y0.x); w1[1] = f32_to_bf16_rne(y0.y);
      w1[2] = f32_to_bf16_rne(y0.z); w1[3] = f32_to_bf16_rne(y0.w);
      w1[4] = f32_to_bf16_rne(y1.x); w1[5] = f32_to_bf16_rne(y1.y);
      w1[6] = f32_to_bf16_rne(y1.z); w1[7] = f32_to_bf16_rne(y1.w);
      *(u16x8*)sAw0 = w0;
      *(u16x8*)sAw1 = w1;
    } else {
      async16(ag0 + k0, sA0);
      async16(ag1 + k0, sA1);
    }
    __syncthreads();

    bf16x8 af[4], bf[4];
    #pragma unroll
    for (int i = 0; i < 4; ++i) {
      af[i] = *(const bf16x8*)(sa_rd + i * 16 * BK);
      bf[i] = *(const bf16x8*)(sb_rd + i * 16 * BK);
    }
    #pragma unroll
    for (int i = 0; i < 4; ++i)
      #pragma unroll
      for (int j = 0; j < 4; ++j)
        acc[i][j] = __builtin_amdgcn_mfma_f32_16x16x32_bf16(af[i], bf[j], acc[i][j], 0, 0, 0);
  }

  const int row0 = (int)a_row0 + wm + (lane >> 4) * 4;
  const int col0 = (int)b_row0 + wn + lrow;
  float bv[4];
  #pragma unroll
  for (int j = 0; j < 4; ++j) bv[j] = bias[col0 + j * 16];
  #pragma unroll
  for (int i = 0; i < 4; ++i)
    #pragma unroll
    for (int j = 0; j < 4; ++j) {
      const int col = col0 + j * 16;
      #pragma unroll
      for (int r = 0; r < 4; ++r) {
        const int row = row0 + i * 16 + r;
        C[(size_t)row * GEMM_N + col] = acc[i][j][r] + bv[j];
      }
    }
}

// ---- kernel 2: 256x256 8-phase GEMM, v2 ------------------------------------
// v2 changes vs round-1 (theory: phase-lockstep serialized LDS service and
// MFMA issue -> 39.5% MfmaUtil):
//  1. barrier#1 removed (1 barrier/phase). Staging safety comes from the
//     end-of-phase barrier alone: every wave's reads complete (compiler
//     lgkm waits) before its MFMAs, before it reaches the barrier, before any
//     wave issues the next phase's STAGE; same-phase STAGE targets are
//     disjoint from same-phase read regions (audited per phase, incl. DMA
//     landing windows vs group-end vmcnt).
//  2. k-split issue order: k0 frags, k1 frags, k0 MFMA cluster (compiler
//     emits counted lgkmcnt(6)/(2) automatically), k1 cluster. k1's LDS
//     service hides under k0's MFMA issue.
//  3. k-major MFMA order: 8 independent MFMAs then 8 at dep-distance 8
//     (was dep-distance 1).
// Staging schedule + counted vmcnt(6) + T2 swizzle + setprio unchanged.

__device__ __forceinline__ bf16x8 lds_ld(const unsigned short* p) {
  return *(const bf16x8*)p;
}

// one k-half cluster: 8 MFMAs, all-independent accs (MLO, MLO+1 x n)
template <int MLO, int KH>
__device__ __forceinline__ void clusterK(f32x4 acc[8][4], bf16x8 aE, bf16x8 aO,
                                         const bf16x8 (&bf)[4][2]) {
#pragma unroll
  for (int n = 0; n < 4; ++n) {
    acc[MLO][n]     = __builtin_amdgcn_mfma_f32_16x16x32_bf16(aE, bf[n][KH], acc[MLO][n], 0, 0, 0);
    acc[MLO + 1][n] = __builtin_amdgcn_mfma_f32_16x16x32_bf16(aO, bf[n][KH], acc[MLO + 1][n], 0, 0, 0);
  }
}

#define BARRIER() asm volatile("s_barrier" ::: "memory")
#define VM6()     asm volatile("s_waitcnt vmcnt(6)" ::: "memory")
#define VM0()     asm volatile("s_waitcnt vmcnt(0)" ::: "memory")

__global__ __launch_bounds__(512, 2) void gemm8p(
    const unsigned short* __restrict__ A,   // [8192,4096] bf16 bits (xb)
    const unsigned short* __restrict__ B,   // [4096,4096] bf16 bits (Wp)
    const float* __restrict__ bias,         // [4096]
    float* __restrict__ C) {                // [8192,4096] fp32
  __shared__ __align__(16) unsigned short sA[2 * 256 * 64];   // 64 KiB
  __shared__ __align__(16) unsigned short sB[2 * 256 * 64];   // 64 KiB

  const int tid  = threadIdx.x;
  const int w    = tid >> 6;       // 0..7
  const int lane = tid & 63;
  const int wm2  = w >> 2;         // 0..1  M half
  const int wn4  = w & 3;          // 0..3  N quarter
  const int l15  = lane & 15;
  const int l16  = lane >> 4;      // 0..3
  const int l7   = lane & 7;

  // XCD-aware bijective swizzle (512 wgs % 8 == 0)
  const int id  = (int)blockIdx.x;
  const int swz = (id & 7) * 64 + (id >> 3);
  const int by  = swz >> 4;        // 0..31 M tile
  const int bx  = swz & 15;        // 0..15 N tile

  const size_t a_row0 = (size_t)by * 256;
  const size_t b_row0 = (size_t)bx * 256;

  // staging: per-lane global src with pre-swizzled 16B column
  const int srow = w * 8 + (lane >> 3);            // row within 64-row chunk
  const int scol = (l7 ^ (lane >> 3)) * 8;         // elements
  const unsigned short* Ag = A + (a_row0 + srow) * (size_t)4096 + scol;
  const unsigned short* Bg = B + (b_row0 + srow) * (size_t)4096 + scol;
  unsigned short* sAw = sA + w * 512;              // + buf*16384 + cr*64
  unsigned short* sBw = sB + w * 512;

  // swizzled LDS read offsets (shorts); row&7 == lane&7 for all fragments
  const int offk0 = l15 * 64 + ((l16    ) ^ l7) * 8;
  const int offk1 = l15 * 64 + ((4 + l16) ^ l7) * 8;

  f32x4 acc[8][4];
  #pragma unroll
  for (int i = 0; i < 8; ++i)
    #pragma unroll
    for (int j = 0; j < 4; ++j) acc[i][j] = (f32x4){0.f, 0.f, 0.f, 0.f};

#define STAGE_A(t, cr, buf) async16(Ag + (size_t)(cr) * 4096 + (t) * 64, sAw + (buf) * 16384 + (cr) * 64)
#define STAGE_B(t, cr, buf) async16(Bg + (size_t)(cr) * 4096 + (t) * 64, sBw + (buf) * 16384 + (cr) * 64)

  // prologue: tile0 full -> buf0; tile1 B all + A rows 0-63,128-191 -> buf1
  STAGE_B(0, 0, 0); STAGE_B(0, 64, 0); STAGE_B(0, 128, 0); STAGE_B(0, 192, 0);
  STAGE_A(0, 0, 0); STAGE_A(0, 64, 0); STAGE_A(0, 128, 0); STAGE_A(0, 192, 0);
  STAGE_B(1, 0, 1); STAGE_B(1, 64, 1); STAGE_B(1, 128, 1); STAGE_B(1, 192, 1);
  STAGE_A(1, 0, 1); STAGE_A(1, 128, 1);
  VM6();            // tile0's 8 loads retired; tile1's 6 in flight
  BARRIER();

  for (int T = 0; T < 64; ++T) {
    const int cb = T & 1, nb = cb ^ 1;
    const unsigned short* sAh = sA + cb * 16384 + wm2 * 8192;
    const unsigned short* sBh = sB + cb * 16384 + wn4 * 4096;
    const bool pre1 = (T + 1 < 64);
    const bool pre2 = (T + 2 < 64);
    bf16x8 bf[4][2];
    bf16x8 a0, a1, a2, a3;

    // -------- phase 0: B frags (k0 then k1) + A m0,m1; MFMA m0,m1 --------
    #pragma unroll
    for (int n = 0; n < 4; ++n) bf[n][0] = lds_ld(sBh + n * 1024 + offk0);
    a0 = lds_ld(sAh + 0 * 1024 + offk0);
    a2 = lds_ld(sAh + 1 * 1024 + offk0);
    #pragma unroll
    for (int n = 0; n < 4; ++n) bf[n][1] = lds_ld(sBh + n * 1024 + offk1);
    a1 = lds_ld(sAh + 0 * 1024 + offk1);
    a3 = lds_ld(sAh + 1 * 1024 + offk1);
    if (pre1) { STAGE_A(T + 1, 64, nb); STAGE_A(T + 1, 192, nb); }
    __builtin_amdgcn_s_setprio(1);
    clusterK<0, 0>(acc, a0, a2, bf);
    clusterK<0, 1>(acc, a1, a3, bf);
    __builtin_amdgcn_s_setprio(0);
    BARRIER();

    // -------- phase 1: A m2,m3 --------
    a0 = lds_ld(sAh + 2 * 1024 + offk0);
    a2 = lds_ld(sAh + 3 * 1024 + offk0);
    a1 = lds_ld(sAh + 2 * 1024 + offk1);
    a3 = lds_ld(sAh + 3 * 1024 + offk1);
    if (pre2) { STAGE_B(T + 2, 0, cb); STAGE_B(T + 2, 64, cb); }
    __builtin_amdgcn_s_setprio(1);
    clusterK<2, 0>(acc, a0, a2, bf);
    clusterK<2, 1>(acc, a1, a3, bf);
    __builtin_amdgcn_s_setprio(0);
    BARRIER();

    // -------- phase 2: A m4,m5 --------
    a0 = lds_ld(sAh + 4 * 1024 + offk0);
    a2 = lds_ld(sAh + 5 * 1024 + offk0);
    a1 = lds_ld(sAh + 4 * 1024 + offk1);
    a3 = lds_ld(sAh + 5 * 1024 + offk1);
    if (pre2) { STAGE_B(T + 2, 128, cb); STAGE_B(T + 2, 192, cb); }
    __builtin_amdgcn_s_setprio(1);
    clusterK<4, 0>(acc, a0, a2, bf);
    clusterK<4, 1>(acc, a1, a3, bf);
    __builtin_amdgcn_s_setprio(0);
    BARRIER();

    // -------- phase 3: A m6,m7 + group checkpoint --------
    a0 = lds_ld(sAh + 6 * 1024 + offk0);
    a2 = lds_ld(sAh + 7 * 1024 + offk0);
    a1 = lds_ld(sAh + 6 * 1024 + offk1);
    a3 = lds_ld(sAh + 7 * 1024 + offk1);
    if (pre2) { STAGE_A(T + 2, 0, cb); STAGE_A(T + 2, 128, cb); }
    __builtin_amdgcn_s_setprio(1);
    clusterK<6, 0>(acc, a0, a2, bf);
    clusterK<6, 1>(acc, a1, a3, bf);
    __builtin_amdgcn_s_setprio(0);
    if (T < 62) { VM6(); } else { VM0(); }   // tile T+1 fully landed
    BARRIER();
  }

  // epilogue: C/D layout col=lane&15, row=(lane>>4)*4+reg (m89-verified)
  const int erow = (int)a_row0 + wm2 * 128 + l16 * 4;
  const int ecol = (int)b_row0 + wn4 * 64 + l15;
  float bv[4];
  #pragma unroll
  for (int n = 0; n < 4; ++n) bv[n] = bias[ecol + n * 16];
  #pragma unroll
  for (int m = 0; m < 8; ++m)
    #pragma unroll
    for (int n = 0; n < 4; ++n) {
      const int col = ecol + n * 16;
      #pragma unroll
      for (int r = 0; r < 4; ++r)
        C[(size_t)(erow + m * 16 + r) * 4096 + col] = acc[m][n][r] + bv[n];
    }
}

#undef STAGE_A
#undef STAGE_B

// ---- launch ----------------------------------------------------------------

extern "C" void kernel_launch(void* const* d_in, const int* in_sizes, int n_in,
                              void* d_out, int out_size, void* d_ws, size_t ws_size,
                              hipStream_t stream) {
  const float* x  = (const float*)d_in[0];   // [4,2048,4096]
  const float* W  = (const float*)d_in[1];   // [4096,4096]
  const float* b  = (const float*)d_in[2];   // [4096]
  const float* lA = (const float*)d_in[3];   // [16,4096]
  const float* lB = (const float*)d_in[4];   // [4096,16]
  float* out = (float*)d_out;                // [4,2048,4096] fp32
  (void)in_sizes; (void)n_in; (void)out_size;

  const size_t WP_BYTES = (size_t)4096 * 4096 * 2;
  const size_t XB_BYTES = (size_t)8192 * 4096 * 2;
  unsigned short* Wp = (unsigned short*)d_ws;

  if (ws_size >= WP_BYTES + XB_BYTES) {
    unsigned short* xb = Wp + (size_t)4096 * 4096;
    prep_fused<<<6144, 256, 0, stream>>>(W, lA, lB, x, Wp, xb);
    gemm8p<<<512, 512, 0, stream>>>(xb, Wp, b, out);
  } else {
    prep_fused<<<2048, 256, 0, stream>>>(W, lA, lB, x, Wp, (unsigned short*)nullptr);
    gemm_bias<true><<<dim3(GEMM_N / BN, GEMM_M / BM), 256, 0, stream>>>(
        (const void*)x, Wp, b, out);
  }
}